// Round 1
// baseline (364.847 us; speedup 1.0000x reference)
//
#include <hip/hip_runtime.h>

// PolyPoolerTextLenSensitive — MI355X (gfx950)
//
// Inputs (setup_inputs order):
//   d_in[0] feat0  (2,256,200,336) f32
//   d_in[1] feat1  (2,256,100,168) f32
//   d_in[2] feat2  (2,256, 50, 84) f32
//   d_in[3] feat3  (2,256, 25, 42) f32
//   d_in[4] polys  (256,14,2)      f32
//   d_in[5] img_ids(256,)          i32
//   d_in[6] lens   (256,)          i32
// Output: out0 (256,256,8,32) then out1 (256,256,8,64), f32, concat flat.

#define NBOX 256
#define NCH  256
#define HP   8
#define CCHUNK 32
#define OUT0_ELEMS ((size_t)NBOX * NCH * HP * 32)

__global__ __launch_bounds__(256) void poly_pool_kernel(
    const float* __restrict__ f0, const float* __restrict__ f1,
    const float* __restrict__ f2, const float* __restrict__ f3,
    const float* __restrict__ polys, const int* __restrict__ img_ids,
    const int* __restrict__ lens, float* __restrict__ out)
{
    const int b    = blockIdx.y;
    const int pidk = blockIdx.z;            // 0 -> (8,32), 1 -> (8,64)
    const int wp   = pidk ? 64 : 32;
    const int npos = HP * wp;               // 256 or 512
    const int c0   = blockIdx.x * CCHUNK;
    const int tid  = threadIdx.x;

    float* outb = out + (pidk ? OUT0_ELEMS : 0) + (size_t)b * NCH * npos;

    // pooler routing: pooler_id = (lens > 8)
    const int pooler = (lens[b] > 8) ? 1 : 0;
    if (pooler != pidk) {
        // this box contributes zeros to this output tensor
        float* p = outb + (size_t)c0 * npos;
        const int total = CCHUNK * npos;
        for (int k = tid; k < total; k += 256) p[k] = 0.0f;
        return;
    }

    __shared__ float pts[28];          // polys[b] : 14 points x 2
    __shared__ int   soff[512][4];     // clamped corner offsets
    __shared__ float swt [512][4];     // mask-folded bilinear weights

    if (tid < 28) pts[tid] = polys[b * 28 + tid];
    __syncthreads();

    // ---- level selection: s = sqrt(dx*dy) over raw points ----
    float minx = pts[0], maxx = pts[0], miny = pts[1], maxy = pts[1];
#pragma unroll
    for (int k = 1; k < 14; ++k) {
        float x = pts[2 * k], y = pts[2 * k + 1];
        minx = fminf(minx, x); maxx = fmaxf(maxx, x);
        miny = fminf(miny, y); maxy = fmaxf(maxy, y);
    }
    float s = sqrtf((maxx - minx) * (maxy - miny));
    int lvl = (int)floorf(4.0f + log2f(s / 224.0f + 1e-6f));
    lvl = min(max(lvl, 2), 5) - 2;

    const float* feat; int H, W;
    switch (lvl) {
        case 0:  feat = f0; H = 200; W = 336; break;
        case 1:  feat = f1; H = 100; W = 168; break;
        case 2:  feat = f2; H = 50;  W = 84;  break;
        default: feat = f3; H = 25;  W = 42;  break;
    }
    const int img = img_ids[b];
    const float* featimg = feat + (size_t)img * NCH * H * W;

    // ---- geometry: one (i,j) grid point per thread (x2 for wp=64) ----
    const float Wf = (float)W, Hf = (float)H;
    for (int pos = tid; pos < npos; pos += 256) {
        int i = pos / wp, j = pos % wp;

        float u = ((j + 0.5f) / (float)wp) * 6.0f;   // n-1 = 6
        int   i0 = (int)floorf(u);
        i0 = min(max(i0, 0), 5);
        float f = u - (float)i0;

        // top points: polys[b, i0], polys[b, i0+1] normalized by (1344, 800)
        float txa = pts[2 * i0]       / 1344.0f, tya = pts[2 * i0 + 1] / 800.0f;
        float txb = pts[2 * i0 + 2]   / 1344.0f, tyb = pts[2 * i0 + 3] / 800.0f;
        // bottom points (reversed): pn[7+m] = polys[b, 13-m]
        int ka = 13 - i0, kb = 12 - i0;
        float bxa = pts[2 * ka] / 1344.0f, bya = pts[2 * ka + 1] / 800.0f;
        float bxb = pts[2 * kb] / 1344.0f, byb = pts[2 * kb + 1] / 800.0f;

        float topx = txa * (1.0f - f) + txb * f;
        float topy = tya * (1.0f - f) + tyb * f;
        float botx = bxa * (1.0f - f) + bxb * f;
        float boty = bya * (1.0f - f) + byb * f;

        float v  = (i + 0.5f) / 8.0f;
        float gx = topx * (1.0f - v) + botx * v;
        float gy = topy * (1.0f - v) + boty * v;

        float x = gx * Wf - 0.5f;
        float y = gy * Hf - 0.5f;
        float x0f = floorf(x), y0f = floorf(y);
        float fx = x - x0f,   fy = y - y0f;
        int x0 = (int)x0f, y0 = (int)y0f;
        int x1 = x0 + 1,   y1 = y0 + 1;

        int x0c = min(max(x0, 0), W - 1), x1c = min(max(x1, 0), W - 1);
        int y0c = min(max(y0, 0), H - 1), y1c = min(max(y1, 0), H - 1);
        float m00 = (x0 >= 0 && x0 < W && y0 >= 0 && y0 < H) ? 1.0f : 0.0f;
        float m10 = (x1 >= 0 && x1 < W && y0 >= 0 && y0 < H) ? 1.0f : 0.0f;
        float m01 = (x0 >= 0 && x0 < W && y1 >= 0 && y1 < H) ? 1.0f : 0.0f;
        float m11 = (x1 >= 0 && x1 < W && y1 >= 0 && y1 < H) ? 1.0f : 0.0f;

        soff[pos][0] = y0c * W + x0c;
        soff[pos][1] = y0c * W + x1c;
        soff[pos][2] = y1c * W + x0c;
        soff[pos][3] = y1c * W + x1c;
        swt [pos][0] = (1.0f - fx) * (1.0f - fy) * m00;
        swt [pos][1] = fx * (1.0f - fy) * m10;
        swt [pos][2] = (1.0f - fx) * fy * m01;
        swt [pos][3] = fx * fy * m11;
    }
    __syncthreads();

    // ---- pull this thread's geometry into registers ----
    const int p0 = tid;
    int   o00 = soff[p0][0], o10 = soff[p0][1], o01 = soff[p0][2], o11 = soff[p0][3];
    float w00 = swt[p0][0],  w10 = swt[p0][1],  w01 = swt[p0][2],  w11 = swt[p0][3];
    const bool two = (npos == 512);
    int   q00 = 0, q10 = 0, q01 = 0, q11 = 0;
    float v00 = 0, v10 = 0, v01 = 0, v11 = 0;
    if (two) {
        const int p1 = tid + 256;
        q00 = soff[p1][0]; q10 = soff[p1][1]; q01 = soff[p1][2]; q11 = soff[p1][3];
        v00 = swt[p1][0];  v10 = swt[p1][1];  v01 = swt[p1][2];  v11 = swt[p1][3];
    }

    // ---- channel loop: 4 gathers + 1 coalesced store per position ----
    for (int c = c0; c < c0 + CCHUNK; ++c) {
        const float* fc = featimg + (size_t)c * H * W;
        float r0 = w00 * fc[o00] + w10 * fc[o10] + w01 * fc[o01] + w11 * fc[o11];
        outb[(size_t)c * npos + p0] = r0;
        if (two) {
            float r1 = v00 * fc[q00] + v10 * fc[q10] + v01 * fc[q01] + v11 * fc[q11];
            outb[(size_t)c * npos + p0 + 256] = r1;
        }
    }
}

extern "C" void kernel_launch(void* const* d_in, const int* in_sizes, int n_in,
                              void* d_out, int out_size, void* d_ws, size_t ws_size,
                              hipStream_t stream) {
    const float* f0    = (const float*)d_in[0];
    const float* f1    = (const float*)d_in[1];
    const float* f2    = (const float*)d_in[2];
    const float* f3    = (const float*)d_in[3];
    const float* polys = (const float*)d_in[4];
    const int*   ids   = (const int*)d_in[5];
    const int*   lens  = (const int*)d_in[6];
    float* out = (float*)d_out;

    dim3 grid(NCH / CCHUNK, NBOX, 2);   // (8, 256, 2)
    poly_pool_kernel<<<grid, 256, 0, stream>>>(f0, f1, f2, f3, polys, ids, lens, out);
}